// Round 1
// baseline (853.980 us; speedup 1.0000x reference)
//
#include <hip/hip_runtime.h>

#define DF4 64  // 256 features / 4 per float4

// ---------------------------------------------------------------- zero fill
__global__ void zero_kernel(int* __restrict__ p, int count) {
    int i = blockIdx.x * blockDim.x + threadIdx.x;
    if (i < count) p[i] = 0;
}

// ---------------------------------------------------------------- degrees
__global__ void degree_kernel(const int* __restrict__ src, const int* __restrict__ dst,
                              int* __restrict__ dout, int* __restrict__ din, int E) {
    int i = blockIdx.x * blockDim.x + threadIdx.x;
    int stride = gridDim.x * blockDim.x;
    for (; i < E; i += stride) {
        atomicAdd(&dout[src[i]], 1);
        atomicAdd(&din[dst[i]], 1);
    }
}

// ---------------------------------------------------------------- scales
__global__ void scale_kernel(const int* __restrict__ d0, const int* __restrict__ d1,
                             const int* __restrict__ d2, const int* __restrict__ d3,
                             float* __restrict__ s0, float* __restrict__ s1,
                             float* __restrict__ s2, float* __restrict__ s3, int n) {
    int i = blockIdx.x * blockDim.x + threadIdx.x;
    if (i >= n) return;
    s0[i] = rsqrtf((float)(d0[i] > 1 ? d0[i] : 1));
    s1[i] = rsqrtf((float)(d1[i] > 1 ? d1[i] : 1));
    s2[i] = rsqrtf((float)(d2[i] > 1 ? d2[i] : 1));
    s3[i] = rsqrtf((float)(d3[i] > 1 ? d3[i] : 1));
}

// ---------------------------------------------------------------- bias sums
__global__ void bias_sum_kernel(const float* __restrict__ b1s, const float* __restrict__ b1u,
                                const float* __restrict__ b2s, const float* __restrict__ b2u,
                                float* __restrict__ bsum1, float* __restrict__ bsum2) {
    int i = threadIdx.x;  // 256 threads
    bsum1[i] = b1s[i] + b1u[i];
    bsum2[i] = b2s[i] + b2u[i];
}

// ---------------------------------------------------------------- exclusive scan (row_ptr)
// One block per relation. Chunked Hillis-Steele over 256-element chunks.
__global__ void scan_kernel(const int* __restrict__ degA, const int* __restrict__ degB,
                            int* __restrict__ rpA, int* __restrict__ rpB, int n) {
    const int* deg = blockIdx.x ? degB : degA;
    int* rp = blockIdx.x ? rpB : rpA;
    __shared__ int sm[256];
    int t = threadIdx.x;
    int running = 0;
    for (int base = 0; base < n; base += 256) {
        int v = (base + t < n) ? deg[base + t] : 0;
        sm[t] = v;
        __syncthreads();
        #pragma unroll
        for (int off = 1; off < 256; off <<= 1) {
            int y = (t >= off) ? sm[t - off] : 0;
            __syncthreads();
            sm[t] += y;
            __syncthreads();
        }
        if (base + t < n) rp[base + t] = running + sm[t] - v;  // exclusive
        int tot = sm[255];
        __syncthreads();
        running += tot;
    }
    if (t == 0) rp[n] = running;
}

// ---------------------------------------------------------------- CSR scatter
__global__ void scatter_kernel(const int* __restrict__ src, const int* __restrict__ dst,
                               const int* __restrict__ rp, int* __restrict__ cur,
                               int* __restrict__ csr, int E) {
    int i = blockIdx.x * blockDim.x + threadIdx.x;
    int stride = gridDim.x * blockDim.x;
    for (; i < E; i += stride) {
        int d = dst[i];
        int pos = rp[d] + atomicAdd(&cur[d], 1);
        csr[pos] = src[i];
    }
}

// ---------------------------------------------------------------- pull aggregation
// One wave per dst node; lane owns float4 of the 256-dim feature row.
// out[v] = s_in[v] * sum_{e: dst=v} s_out[src_e] * x[src_e]
__global__ __launch_bounds__(256) void pull_agg_kernel(
    const float4* __restrict__ xin, const int* __restrict__ csr,
    const int* __restrict__ rp, const float* __restrict__ sout,
    const float* __restrict__ sin, float4* __restrict__ out, int n) {
    int wid = blockIdx.x * 4 + (threadIdx.x >> 6);
    int lane = threadIdx.x & 63;
    if (wid >= n) return;
    int beg = rp[wid], end = rp[wid + 1];
    float ax = 0.f, ay = 0.f, az = 0.f, aw = 0.f;
    int e = beg;
    for (; e + 2 <= end; e += 2) {
        int u0 = csr[e], u1 = csr[e + 1];
        float w0 = sout[u0], w1 = sout[u1];
        float4 a = xin[u0 * DF4 + lane];
        float4 b = xin[u1 * DF4 + lane];
        ax += w0 * a.x + w1 * b.x;
        ay += w0 * a.y + w1 * b.y;
        az += w0 * a.z + w1 * b.z;
        aw += w0 * a.w + w1 * b.w;
    }
    if (e < end) {
        int u0 = csr[e];
        float w0 = sout[u0];
        float4 a = xin[u0 * DF4 + lane];
        ax += w0 * a.x; ay += w0 * a.y; az += w0 * a.z; aw += w0 * a.w;
    }
    float si = sin[wid];
    out[wid * DF4 + lane] = make_float4(si * ax, si * ay, si * az, si * aw);
}

// ---------------------------------------------------------------- fp32 GEMM
// C[M x 256] (+)= A[M x 256] @ B[256 x 256] (+bias) (+relu)
// BM=128 BN=64 BK=16, 256 threads, thread tile 4x8.
template <int BETA0, int RELU>
__global__ __launch_bounds__(256) void gemm_kernel(
    const float* __restrict__ A, const float* __restrict__ B,
    const float* __restrict__ bias, float* __restrict__ C, int M) {
    __shared__ float At[16][132];  // [k][row], padded: 8*132 % 32 != 0
    __shared__ float Bs[16][64];   // [k][n]
    int tid = threadIdx.x;
    int ty = tid >> 3;   // 0..31 -> 4 rows each
    int tx = tid & 7;    // 0..7  -> 8 cols each
    int m0 = blockIdx.x * 128;
    int n0 = blockIdx.y * 64;
    const float4* A4 = (const float4*)A;
    const float4* B4 = (const float4*)B;
    float acc[4][8] = {};

    for (int ko = 0; ko < 16; ++ko) {
        // stage A tile transposed: At[k][row]
        #pragma unroll
        for (int q = 0; q < 2; ++q) {
            int idx = q * 256 + tid;       // 0..511
            int row = idx & 127;
            int kc = idx >> 7;             // 0..3
            float4 av = make_float4(0.f, 0.f, 0.f, 0.f);
            int gm = m0 + row;
            if (gm < M) av = A4[gm * 64 + ko * 4 + kc];
            At[kc * 4 + 0][row] = av.x;
            At[kc * 4 + 1][row] = av.y;
            At[kc * 4 + 2][row] = av.z;
            At[kc * 4 + 3][row] = av.w;
        }
        // stage B tile: Bs[k][n]
        {
            int brow = tid >> 4;           // 0..15
            int bc = tid & 15;             // 0..15
            *(float4*)&Bs[brow][bc * 4] = B4[(ko * 16 + brow) * 64 + (n0 >> 2) + bc];
        }
        __syncthreads();
        #pragma unroll
        for (int k = 0; k < 16; ++k) {
            float4 a = *(const float4*)&At[k][ty * 4];
            float4 b0 = *(const float4*)&Bs[k][tx * 8];
            float4 b1 = *(const float4*)&Bs[k][tx * 8 + 4];
            float ar[4] = {a.x, a.y, a.z, a.w};
            float br[8] = {b0.x, b0.y, b0.z, b0.w, b1.x, b1.y, b1.z, b1.w};
            #pragma unroll
            for (int i = 0; i < 4; ++i)
                #pragma unroll
                for (int j = 0; j < 8; ++j)
                    acc[i][j] += ar[i] * br[j];
        }
        __syncthreads();
    }

    float bcol[8];
    if (BETA0) {
        #pragma unroll
        for (int j = 0; j < 8; ++j) bcol[j] = bias[n0 + tx * 8 + j];
    }
    #pragma unroll
    for (int i = 0; i < 4; ++i) {
        int gm = m0 + ty * 4 + i;
        if (gm >= M) continue;
        float4* Crow = (float4*)&C[gm * 256 + n0 + tx * 8];
        float v[8];
        #pragma unroll
        for (int j = 0; j < 8; ++j) v[j] = acc[i][j] + (BETA0 ? bcol[j] : 0.f);
        if (!BETA0) {
            float4 c0 = Crow[0], c1 = Crow[1];
            v[0] += c0.x; v[1] += c0.y; v[2] += c0.z; v[3] += c0.w;
            v[4] += c1.x; v[5] += c1.y; v[6] += c1.z; v[7] += c1.w;
        }
        if (RELU) {
            #pragma unroll
            for (int j = 0; j < 8; ++j) v[j] = fmaxf(v[j], 0.f);
        }
        Crow[0] = make_float4(v[0], v[1], v[2], v[3]);
        Crow[1] = make_float4(v[4], v[5], v[6], v[7]);
    }
}

// ---------------------------------------------------------------- launch
extern "C" void kernel_launch(void* const* d_in, const int* in_sizes, int n_in,
                              void* d_out, int out_size, void* d_ws, size_t ws_size,
                              hipStream_t stream) {
    const float* x   = (const float*)d_in[0];
    const int* sS    = (const int*)d_in[1];
    const int* dS    = (const int*)d_in[2];
    const int* sU    = (const int*)d_in[3];
    const int* dU    = (const int*)d_in[4];
    const float* W1s = (const float*)d_in[5];
    const float* b1s = (const float*)d_in[6];
    const float* W1u = (const float*)d_in[7];
    const float* b1u = (const float*)d_in[8];
    const float* W2s = (const float*)d_in[9];
    const float* b2s = (const float*)d_in[10];
    const float* W2u = (const float*)d_in[11];
    const float* b2u = (const float*)d_in[12];
    float* out = (float*)d_out;

    const int n  = in_sizes[0] / 256;
    const int Es = in_sizes[1];
    const int Eu = in_sizes[3];

    char* ws = (char*)d_ws;
    size_t off = 0;
    auto alloc = [&](size_t bytes) -> void* {
        off = (off + 255) & ~(size_t)255;
        void* p = ws + off;
        off += bytes;
        return p;
    };

    // contiguous zeroed int region: degOutS, degInS, degOutU, degInU, curS, curU
    int* zeros   = (int*)alloc((size_t)6 * n * 4);
    int* degOutS = zeros;
    int* degInS  = zeros + n;
    int* degOutU = zeros + 2 * n;
    int* degInU  = zeros + 3 * n;
    int* curS    = zeros + 4 * n;
    int* curU    = zeros + 5 * n;
    int* rpS     = (int*)alloc((size_t)(n + 1) * 4);
    int* rpU     = (int*)alloc((size_t)(n + 1) * 4);
    float* sOutS = (float*)alloc((size_t)n * 4);
    float* sInS  = (float*)alloc((size_t)n * 4);
    float* sOutU = (float*)alloc((size_t)n * 4);
    float* sInU  = (float*)alloc((size_t)n * 4);
    float* bsum1 = (float*)alloc(256 * 4);
    float* bsum2 = (float*)alloc(256 * 4);
    int* csrS    = (int*)alloc((size_t)Es * 4);
    int* csrU    = (int*)alloc((size_t)Eu * 4);
    float* aggA  = (float*)alloc((size_t)n * 256 * 4);
    float* h     = (float*)alloc((size_t)n * 256 * 4);

    // 1. zero counters
    int zc = 6 * n;
    zero_kernel<<<(zc + 255) / 256, 256, 0, stream>>>(zeros, zc);
    // 2. bias sums
    bias_sum_kernel<<<1, 256, 0, stream>>>(b1s, b1u, b2s, b2u, bsum1, bsum2);
    // 3. degrees
    degree_kernel<<<(Es + 255) / 256, 256, 0, stream>>>(sS, dS, degOutS, degInS, Es);
    degree_kernel<<<(Eu + 255) / 256, 256, 0, stream>>>(sU, dU, degOutU, degInU, Eu);
    // 4. normalization scales
    scale_kernel<<<(n + 255) / 256, 256, 0, stream>>>(degOutS, degInS, degOutU, degInU,
                                                      sOutS, sInS, sOutU, sInU, n);
    // 5. row_ptr (exclusive scan of deg_in)
    scan_kernel<<<2, 256, 0, stream>>>(degInS, degInU, rpS, rpU, n);
    // 6. CSR scatter
    scatter_kernel<<<(Es + 255) / 256, 256, 0, stream>>>(sS, dS, rpS, curS, csrS, Es);
    scatter_kernel<<<(Eu + 255) / 256, 256, 0, stream>>>(sU, dU, rpU, curU, csrU, Eu);

    const float4* x4 = (const float4*)x;
    float4* agg4 = (float4*)aggA;
    int aggGrid = (n + 3) / 4;
    dim3 ggrid((n + 127) / 128, 4);

    // ---- layer 1: h = relu(aggS@W1s + aggU@W1u + b1s + b1u)
    pull_agg_kernel<<<aggGrid, 256, 0, stream>>>(x4, csrS, rpS, sOutS, sInS, agg4, n);
    gemm_kernel<1, 0><<<ggrid, 256, 0, stream>>>(aggA, W1s, bsum1, h, n);
    pull_agg_kernel<<<aggGrid, 256, 0, stream>>>(x4, csrU, rpU, sOutU, sInU, agg4, n);
    gemm_kernel<0, 1><<<ggrid, 256, 0, stream>>>(aggA, W1u, nullptr, h, n);

    // ---- layer 2: out = aggS@W2s + aggU@W2u + b2s + b2u
    const float4* h4 = (const float4*)h;
    pull_agg_kernel<<<aggGrid, 256, 0, stream>>>(h4, csrS, rpS, sOutS, sInS, agg4, n);
    gemm_kernel<1, 0><<<ggrid, 256, 0, stream>>>(aggA, W2s, bsum2, out, n);
    pull_agg_kernel<<<aggGrid, 256, 0, stream>>>(h4, csrU, rpU, sOutU, sInU, agg4, n);
    gemm_kernel<0, 0><<<ggrid, 256, 0, stream>>>(aggA, W2u, nullptr, out, n);
}

// Round 2
// 757.092 us; speedup vs baseline: 1.1280x; 1.1280x over previous
//
#include <hip/hip_runtime.h>

#define SCHUNK 2048  // elements per scan block (256 threads x 8)

// ---------------------------------------------------------------- zero fill
__global__ void zero_kernel(int* __restrict__ p, int count) {
    int i = blockIdx.x * blockDim.x + threadIdx.x;
    if (i < count) p[i] = 0;
}

// ---------------------------------------------------------------- bias sums
__global__ void bias_sum_kernel(const float* __restrict__ b1s, const float* __restrict__ b1u,
                                const float* __restrict__ b2s, const float* __restrict__ b2u,
                                float* __restrict__ bsum1, float* __restrict__ bsum2) {
    int i = threadIdx.x;  // 256 threads
    bsum1[i] = b1s[i] + b1u[i];
    bsum2[i] = b2s[i] + b2u[i];
}

// ---------------------------------------------------------------- degrees (both relations)
__global__ void degree2_kernel(const int* __restrict__ sS, const int* __restrict__ dS,
                               const int* __restrict__ sU, const int* __restrict__ dU,
                               int* __restrict__ doS, int* __restrict__ diS,
                               int* __restrict__ doU, int* __restrict__ diU,
                               int Es, int Eu) {
    const int rel = blockIdx.y;
    const int* src = rel ? sU : sS;
    const int* dst = rel ? dU : dS;
    int* dout = rel ? doU : doS;
    int* din  = rel ? diU : diS;
    int E = rel ? Eu : Es;
    int i = blockIdx.x * blockDim.x + threadIdx.x;
    int stride = gridDim.x * blockDim.x;
    for (; i < E; i += stride) {
        atomicAdd(&dout[src[i]], 1);
        atomicAdd(&din[dst[i]], 1);
    }
}

// ---------------------------------------------------------------- scales
__global__ void scale_kernel(const int* __restrict__ d0, const int* __restrict__ d1,
                             const int* __restrict__ d2, const int* __restrict__ d3,
                             float* __restrict__ s0, float* __restrict__ s1,
                             float* __restrict__ s2, float* __restrict__ s3, int n) {
    int i = blockIdx.x * blockDim.x + threadIdx.x;
    if (i >= n) return;
    s0[i] = rsqrtf((float)(d0[i] > 1 ? d0[i] : 1));
    s1[i] = rsqrtf((float)(d1[i] > 1 ? d1[i] : 1));
    s2[i] = rsqrtf((float)(d2[i] > 1 ? d2[i] : 1));
    s3[i] = rsqrtf((float)(d3[i] > 1 ? d3[i] : 1));
}

// ---------------------------------------------------------------- scan phase 1: block sums
__global__ __launch_bounds__(256) void scan_part_kernel(const int* __restrict__ degA,
                                                        const int* __restrict__ degB,
                                                        int n, int NB, int* __restrict__ bsum) {
    const int rel = blockIdx.y;
    const int* deg = rel ? degB : degA;
    int t = threadIdx.x;
    int base = blockIdx.x * SCHUNK + t * 8;
    int s = 0;
    if (base + 8 <= n) {
        int4 a = *(const int4*)(deg + base);
        int4 b = *(const int4*)(deg + base + 4);
        s = a.x + a.y + a.z + a.w + b.x + b.y + b.z + b.w;
    } else {
        for (int i = 0; i < 8; ++i)
            if (base + i < n) s += deg[base + i];
    }
    __shared__ int sm[256];
    sm[t] = s;
    __syncthreads();
    for (int off = 128; off > 0; off >>= 1) {
        if (t < off) sm[t] += sm[t + off];
        __syncthreads();
    }
    if (t == 0) bsum[rel * NB + blockIdx.x] = sm[0];
}

// ---------------------------------------------------------------- scan phase 2: scan of block sums
__global__ void scan_mid_kernel(int* __restrict__ bsum, int NB,
                                int* __restrict__ rpA, int* __restrict__ rpB, int n) {
    int t = threadIdx.x;
    if (t >= 2) return;
    int* bs = bsum + t * NB;
    int run = 0;
    for (int i = 0; i < NB; ++i) {
        int v = bs[i];
        bs[i] = run;
        run += v;
    }
    int* rp = t ? rpB : rpA;
    rp[n] = run;
}

// ---------------------------------------------------------------- scan phase 3: final exclusive scan
__global__ __launch_bounds__(256) void scan_final_kernel(const int* __restrict__ degA,
                                                         const int* __restrict__ degB,
                                                         const int* __restrict__ bsum,
                                                         int n, int NB,
                                                         int* __restrict__ rpA,
                                                         int* __restrict__ rpB) {
    const int rel = blockIdx.y;
    const int* deg = rel ? degB : degA;
    int* rp = rel ? rpB : rpA;
    int t = threadIdx.x;
    int base = blockIdx.x * SCHUNK + t * 8;
    int v[8];
    if (base + 8 <= n) {
        int4 a = *(const int4*)(deg + base);
        int4 b = *(const int4*)(deg + base + 4);
        v[0] = a.x; v[1] = a.y; v[2] = a.z; v[3] = a.w;
        v[4] = b.x; v[5] = b.y; v[6] = b.z; v[7] = b.w;
    } else {
        for (int i = 0; i < 8; ++i) v[i] = (base + i < n) ? deg[base + i] : 0;
    }
    int s = 0;
    #pragma unroll
    for (int i = 0; i < 8; ++i) s += v[i];
    __shared__ int sm[256];
    sm[t] = s;
    __syncthreads();
    #pragma unroll
    for (int off = 1; off < 256; off <<= 1) {
        int y = (t >= off) ? sm[t - off] : 0;
        __syncthreads();
        sm[t] += y;
        __syncthreads();
    }
    int run = bsum[rel * NB + blockIdx.x] + sm[t] - s;  // exclusive prefix for this thread
    #pragma unroll
    for (int i = 0; i < 8; ++i) {
        if (base + i < n) rp[base + i] = run;
        run += v[i];
    }
}

// ---------------------------------------------------------------- CSR scatter (both relations)
__global__ void scatter2_kernel(const int* __restrict__ sS, const int* __restrict__ dS,
                                const int* __restrict__ sU, const int* __restrict__ dU,
                                const int* __restrict__ rpS, const int* __restrict__ rpU,
                                int* __restrict__ curS, int* __restrict__ curU,
                                int* __restrict__ csrS, int* __restrict__ csrU,
                                int Es, int Eu) {
    const int rel = blockIdx.y;
    const int* src = rel ? sU : sS;
    const int* dst = rel ? dU : dS;
    const int* rp = rel ? rpU : rpS;
    int* cur = rel ? curU : curS;
    int* csr = rel ? csrU : csrS;
    int E = rel ? Eu : Es;
    int i = blockIdx.x * blockDim.x + threadIdx.x;
    int stride = gridDim.x * blockDim.x;
    for (; i < E; i += stride) {
        int d = dst[i];
        int pos = rp[d] + atomicAdd(&cur[d], 1);
        csr[pos] = src[i];
    }
}

// ---------------------------------------------------------------- pull aggregation
// One wave per dst node; lane owns a float4 of the 256-dim row.
// Edge indices + weights loaded coalesced 64-wide, broadcast via shfl:
// keeps only the coalesced x-row gather on the dependent chain.
__global__ __launch_bounds__(256) void pull_agg_kernel(
    const float4* __restrict__ xin, const int* __restrict__ csr,
    const int* __restrict__ rp, const float* __restrict__ sout,
    const float* __restrict__ sin, float4* __restrict__ out,
    int ostride4, int n) {
    int wid = blockIdx.x * 4 + (threadIdx.x >> 6);
    int lane = threadIdx.x & 63;
    if (wid >= n) return;
    int beg = rp[wid], end = rp[wid + 1];
    float ax = 0.f, ay = 0.f, az = 0.f, aw = 0.f;
    for (int eb = beg; eb < end; eb += 64) {
        int cnt = end - eb;
        if (cnt > 64) cnt = 64;
        int myu = 0;
        float myw = 0.f;
        if (lane < cnt) {
            myu = csr[eb + lane];
            myw = sout[myu];
        }
        for (int j = 0; j < cnt; ++j) {
            int u = __shfl(myu, j);
            float w = __shfl(myw, j);
            float4 a = xin[u * 64 + lane];
            ax += w * a.x;
            ay += w * a.y;
            az += w * a.z;
            aw += w * a.w;
        }
    }
    float si = sin[wid];
    out[wid * ostride4 + lane] = make_float4(si * ax, si * ay, si * az, si * aw);
}

// ---------------------------------------------------------------- fp32 GEMM
// C[M x 256] (+)= A[M x K] @ [B0;B1][K x 256] (+bias) (+relu)
// B0 serves rows k<256, B1 rows k>=256 (concat-K). BM=128 BN=64 BK=16,
// 256 threads, 4x8 per-thread tile.
template <int BETA0, int RELU>
__global__ __launch_bounds__(256) void gemm_kernel(
    const float* __restrict__ A, const float* __restrict__ B0,
    const float* __restrict__ B1, const float* __restrict__ bias,
    float* __restrict__ C, int M, int KB, int lda4) {
    __shared__ float At[16][132];  // [k][row], padded
    __shared__ float Bs[16][64];   // [k][n]
    int tid = threadIdx.x;
    int ty = tid >> 3;   // 0..31 -> 4 rows each
    int tx = tid & 7;    // 0..7  -> 8 cols each
    int m0 = blockIdx.x * 128;
    int n0 = blockIdx.y * 64;
    const float4* A4 = (const float4*)A;
    const float4* B04 = (const float4*)B0;
    const float4* B14 = (const float4*)B1;
    float acc[4][8] = {};

    for (int ko = 0; ko < KB; ++ko) {
        #pragma unroll
        for (int q = 0; q < 2; ++q) {
            int idx = q * 256 + tid;       // 0..511
            int row = idx & 127;
            int kc = idx >> 7;             // 0..3
            float4 av = make_float4(0.f, 0.f, 0.f, 0.f);
            int gm = m0 + row;
            if (gm < M) av = A4[(size_t)gm * lda4 + ko * 4 + kc];
            At[kc * 4 + 0][row] = av.x;
            At[kc * 4 + 1][row] = av.y;
            At[kc * 4 + 2][row] = av.z;
            At[kc * 4 + 3][row] = av.w;
        }
        {
            int brow = tid >> 4;           // 0..15
            int bc = tid & 15;             // 0..15
            int kg = ko * 16 + brow;
            const float4* Brow = (kg < 256) ? (B04 + (size_t)kg * 64)
                                            : (B14 + (size_t)(kg - 256) * 64);
            *(float4*)&Bs[brow][bc * 4] = Brow[(n0 >> 2) + bc];
        }
        __syncthreads();
        #pragma unroll
        for (int k = 0; k < 16; ++k) {
            float4 a = *(const float4*)&At[k][ty * 4];
            float4 b0 = *(const float4*)&Bs[k][tx * 8];
            float4 b1 = *(const float4*)&Bs[k][tx * 8 + 4];
            float ar[4] = {a.x, a.y, a.z, a.w};
            float br[8] = {b0.x, b0.y, b0.z, b0.w, b1.x, b1.y, b1.z, b1.w};
            #pragma unroll
            for (int i = 0; i < 4; ++i)
                #pragma unroll
                for (int j = 0; j < 8; ++j)
                    acc[i][j] += ar[i] * br[j];
        }
        __syncthreads();
    }

    float bcol[8];
    if (BETA0) {
        #pragma unroll
        for (int j = 0; j < 8; ++j) bcol[j] = bias[n0 + tx * 8 + j];
    }
    #pragma unroll
    for (int i = 0; i < 4; ++i) {
        int gm = m0 + ty * 4 + i;
        if (gm >= M) continue;
        float4* Crow = (float4*)&C[(size_t)gm * 256 + n0 + tx * 8];
        float v[8];
        #pragma unroll
        for (int j = 0; j < 8; ++j) v[j] = acc[i][j] + (BETA0 ? bcol[j] : 0.f);
        if (!BETA0) {
            float4 c0 = Crow[0], c1 = Crow[1];
            v[0] += c0.x; v[1] += c0.y; v[2] += c0.z; v[3] += c0.w;
            v[4] += c1.x; v[5] += c1.y; v[6] += c1.z; v[7] += c1.w;
        }
        if (RELU) {
            #pragma unroll
            for (int j = 0; j < 8; ++j) v[j] = fmaxf(v[j], 0.f);
        }
        Crow[0] = make_float4(v[0], v[1], v[2], v[3]);
        Crow[1] = make_float4(v[4], v[5], v[6], v[7]);
    }
}

// ---------------------------------------------------------------- launch
extern "C" void kernel_launch(void* const* d_in, const int* in_sizes, int n_in,
                              void* d_out, int out_size, void* d_ws, size_t ws_size,
                              hipStream_t stream) {
    const float* x   = (const float*)d_in[0];
    const int* sS    = (const int*)d_in[1];
    const int* dS    = (const int*)d_in[2];
    const int* sU    = (const int*)d_in[3];
    const int* dU    = (const int*)d_in[4];
    const float* W1s = (const float*)d_in[5];
    const float* b1s = (const float*)d_in[6];
    const float* W1u = (const float*)d_in[7];
    const float* b1u = (const float*)d_in[8];
    const float* W2s = (const float*)d_in[9];
    const float* b2s = (const float*)d_in[10];
    const float* W2u = (const float*)d_in[11];
    const float* b2u = (const float*)d_in[12];
    float* out = (float*)d_out;

    const int n  = in_sizes[0] / 256;
    const int Es = in_sizes[1];
    const int Eu = in_sizes[3];
    const int NB = (n + SCHUNK - 1) / SCHUNK;
    const int na = (n + 63) & ~63;  // 256B-aligned stride for deg arrays

    char* ws = (char*)d_ws;
    size_t off = 0;
    auto alloc = [&](size_t bytes) -> void* {
        off = (off + 255) & ~(size_t)255;
        void* p = ws + off;
        off += bytes;
        return p;
    };

    // contiguous zeroed region: degOutS, degInS, degOutU, degInU, curS, curU
    int* zeros   = (int*)alloc((size_t)6 * na * 4);
    int* degOutS = zeros;
    int* degInS  = zeros + na;
    int* degOutU = zeros + 2 * na;
    int* degInU  = zeros + 3 * na;
    int* curS    = zeros + 4 * na;
    int* curU    = zeros + 5 * na;
    int* rpS     = (int*)alloc((size_t)(n + 1) * 4);
    int* rpU     = (int*)alloc((size_t)(n + 1) * 4);
    float* sOutS = (float*)alloc((size_t)n * 4);
    float* sInS  = (float*)alloc((size_t)n * 4);
    float* sOutU = (float*)alloc((size_t)n * 4);
    float* sInU  = (float*)alloc((size_t)n * 4);
    float* bsum1 = (float*)alloc(256 * 4);
    float* bsum2 = (float*)alloc(256 * 4);
    int* bsumBlk = (int*)alloc((size_t)2 * NB * 4);
    int* csrS    = (int*)alloc((size_t)Es * 4);
    int* csrU    = (int*)alloc((size_t)Eu * 4);

    // Fused path needs aggCat n x 512; fallback n x 256.
    size_t fixed = off;
    size_t need_fused = ((fixed + 255) & ~(size_t)255) + (size_t)n * 512 * 4 + 256 +
                        (size_t)n * 256 * 4 + 256;
    bool fused = need_fused <= ws_size;
    float* aggCat = (float*)alloc((size_t)n * (fused ? 512 : 256) * 4);
    float* h      = (float*)alloc((size_t)n * 256 * 4);

    // 1. zero counters
    int zc = 6 * na;
    zero_kernel<<<(zc + 255) / 256, 256, 0, stream>>>(zeros, zc);
    // 2. bias sums
    bias_sum_kernel<<<1, 256, 0, stream>>>(b1s, b1u, b2s, b2u, bsum1, bsum2);
    // 3. degrees (both relations, one launch)
    int Emax = Es > Eu ? Es : Eu;
    dim3 dg((Emax + 255) / 256, 2);
    degree2_kernel<<<dg, 256, 0, stream>>>(sS, dS, sU, dU,
                                           degOutS, degInS, degOutU, degInU, Es, Eu);
    // 4. normalization scales
    scale_kernel<<<(n + 255) / 256, 256, 0, stream>>>(degOutS, degInS, degOutU, degInU,
                                                      sOutS, sInS, sOutU, sInU, n);
    // 5. parallel exclusive scan of deg_in -> row_ptr
    dim3 sg(NB, 2);
    scan_part_kernel<<<sg, 256, 0, stream>>>(degInS, degInU, n, NB, bsumBlk);
    scan_mid_kernel<<<1, 64, 0, stream>>>(bsumBlk, NB, rpS, rpU, n);
    scan_final_kernel<<<sg, 256, 0, stream>>>(degInS, degInU, bsumBlk, n, NB, rpS, rpU);
    // 6. CSR scatter (both relations, one launch)
    scatter2_kernel<<<dg, 256, 0, stream>>>(sS, dS, sU, dU, rpS, rpU,
                                            curS, curU, csrS, csrU, Es, Eu);

    const float4* x4 = (const float4*)x;
    const float4* h4 = (const float4*)h;
    float4* agg4 = (float4*)aggCat;
    int aggGrid = (n + 3) / 4;
    dim3 ggrid((n + 127) / 128, 4);

    if (fused) {
        // layer 1: h = relu([aggS|aggU] @ [W1s;W1u] + bsum1)
        pull_agg_kernel<<<aggGrid, 256, 0, stream>>>(x4, csrS, rpS, sOutS, sInS, agg4, 128, n);
        pull_agg_kernel<<<aggGrid, 256, 0, stream>>>(x4, csrU, rpU, sOutU, sInU, agg4 + 64, 128, n);
        gemm_kernel<1, 1><<<ggrid, 256, 0, stream>>>(aggCat, W1s, W1u, bsum1, h, n, 32, 128);
        // layer 2
        pull_agg_kernel<<<aggGrid, 256, 0, stream>>>(h4, csrS, rpS, sOutS, sInS, agg4, 128, n);
        pull_agg_kernel<<<aggGrid, 256, 0, stream>>>(h4, csrU, rpU, sOutU, sInU, agg4 + 64, 128, n);
        gemm_kernel<1, 0><<<ggrid, 256, 0, stream>>>(aggCat, W2s, W2u, bsum2, out, n, 32, 128);
    } else {
        // fallback: 4 GEMMs with accumulation
        pull_agg_kernel<<<aggGrid, 256, 0, stream>>>(x4, csrS, rpS, sOutS, sInS, agg4, 64, n);
        gemm_kernel<1, 0><<<ggrid, 256, 0, stream>>>(aggCat, W1s, W1s, bsum1, h, n, 16, 64);
        pull_agg_kernel<<<aggGrid, 256, 0, stream>>>(x4, csrU, rpU, sOutU, sInU, agg4, 64, n);
        gemm_kernel<0, 1><<<ggrid, 256, 0, stream>>>(aggCat, W1u, W1u, nullptr, h, n, 16, 64);
        pull_agg_kernel<<<aggGrid, 256, 0, stream>>>(h4, csrS, rpS, sOutS, sInS, agg4, 64, n);
        gemm_kernel<1, 0><<<ggrid, 256, 0, stream>>>(aggCat, W2s, W2s, bsum2, out, n, 16, 64);
        pull_agg_kernel<<<aggGrid, 256, 0, stream>>>(h4, csrU, rpU, sOutU, sInU, agg4, 64, n);
        gemm_kernel<0, 0><<<ggrid, 256, 0, stream>>>(aggCat, W2u, W2u, nullptr, out, n, 16, 64);
    }
}

// Round 3
// 676.690 us; speedup vs baseline: 1.2620x; 1.1188x over previous
//
#include <hip/hip_runtime.h>

#define SCHUNK 2048   // elements per scan block (256 threads x 8)
#define NBLK   32     // histogram blocks per relation (chunk <= 65535 for 16-bit packing)
#define MAXN   20480  // LDS histogram capacity (n = 20000)

// ---------------------------------------------------------------- bias sums
__global__ void bias_sum_kernel(const float* __restrict__ b1s, const float* __restrict__ b1u,
                                const float* __restrict__ b2s, const float* __restrict__ b2u,
                                float* __restrict__ bsum1, float* __restrict__ bsum2) {
    int i = threadIdx.x;  // 256 threads
    bsum1[i] = b1s[i] + b1u[i];
    bsum2[i] = b2s[i] + b2u[i];
}

// ---------------------------------------------------------------- phase H: per-block packed histograms
// packed: low 16 bits = src count (deg_out), high 16 = dst count (deg_in)
__global__ __launch_bounds__(256) void hist_kernel(
    const int* __restrict__ sS, const int* __restrict__ dS,
    const int* __restrict__ sU, const int* __restrict__ dU,
    int Es, int Eu, int n, unsigned int* __restrict__ histG /* [2][NBLK][n] */) {
    __shared__ unsigned int h[MAXN];
    const int rel = blockIdx.y;
    const int* src = rel ? sU : sS;
    const int* dst = rel ? dU : dS;
    int E = rel ? Eu : Es;
    int b = blockIdx.x;
    int chunk = (E + NBLK - 1) / NBLK;
    int beg = b * chunk;
    int end = min(E, beg + chunk);
    for (int i = threadIdx.x; i < n; i += 256) h[i] = 0u;
    __syncthreads();
    for (int i = beg + threadIdx.x; i < end; i += 256) {
        atomicAdd(&h[src[i]], 1u);
        atomicAdd(&h[dst[i]], 0x10000u);
    }
    __syncthreads();
    unsigned int* out = histG + ((size_t)rel * NBLK + b) * n;
    for (int i = threadIdx.x; i < n; i += 256) out[i] = h[i];
}

// ---------------------------------------------------------------- phase B1: totals -> scales + deg_in
__global__ void totals_kernel(const unsigned int* __restrict__ histG, int n,
                              float* __restrict__ sOutS, float* __restrict__ sInS,
                              float* __restrict__ sOutU, float* __restrict__ sInU,
                              int* __restrict__ degInS, int* __restrict__ degInU) {
    const int rel = blockIdx.y;
    int i = blockIdx.x * 256 + threadIdx.x;
    if (i >= n) return;
    const unsigned int* hg = histG + (size_t)rel * NBLK * n;
    unsigned int lo = 0, hi = 0;
    #pragma unroll
    for (int b = 0; b < NBLK; ++b) {
        unsigned int v = hg[(size_t)b * n + i];
        lo += v & 0xFFFFu;
        hi += v >> 16;
    }
    float so = rsqrtf((float)(lo > 1u ? lo : 1u));
    float si = rsqrtf((float)(hi > 1u ? hi : 1u));
    if (rel) { sOutU[i] = so; sInU[i] = si; degInU[i] = (int)hi; }
    else     { sOutS[i] = so; sInS[i] = si; degInS[i] = (int)hi; }
}

// ---------------------------------------------------------------- scan phase 1: block sums
__global__ __launch_bounds__(256) void scan_part_kernel(const int* __restrict__ degA,
                                                        const int* __restrict__ degB,
                                                        int n, int NB, int* __restrict__ bsum) {
    const int rel = blockIdx.y;
    const int* deg = rel ? degB : degA;
    int t = threadIdx.x;
    int base = blockIdx.x * SCHUNK + t * 8;
    int s = 0;
    if (base + 8 <= n) {
        int4 a = *(const int4*)(deg + base);
        int4 b = *(const int4*)(deg + base + 4);
        s = a.x + a.y + a.z + a.w + b.x + b.y + b.z + b.w;
    } else {
        for (int i = 0; i < 8; ++i)
            if (base + i < n) s += deg[base + i];
    }
    __shared__ int sm[256];
    sm[t] = s;
    __syncthreads();
    for (int off = 128; off > 0; off >>= 1) {
        if (t < off) sm[t] += sm[t + off];
        __syncthreads();
    }
    if (t == 0) bsum[rel * NB + blockIdx.x] = sm[0];
}

// ---------------------------------------------------------------- scan phase 2
__global__ void scan_mid_kernel(int* __restrict__ bsum, int NB,
                                int* __restrict__ rpA, int* __restrict__ rpB, int n) {
    int t = threadIdx.x;
    if (t >= 2) return;
    int* bs = bsum + t * NB;
    int run = 0;
    for (int i = 0; i < NB; ++i) {
        int v = bs[i];
        bs[i] = run;
        run += v;
    }
    int* rp = t ? rpB : rpA;
    rp[n] = run;
}

// ---------------------------------------------------------------- scan phase 3
__global__ __launch_bounds__(256) void scan_final_kernel(const int* __restrict__ degA,
                                                         const int* __restrict__ degB,
                                                         const int* __restrict__ bsum,
                                                         int n, int NB,
                                                         int* __restrict__ rpA,
                                                         int* __restrict__ rpB) {
    const int rel = blockIdx.y;
    const int* deg = rel ? degB : degA;
    int* rp = rel ? rpB : rpA;
    int t = threadIdx.x;
    int base = blockIdx.x * SCHUNK + t * 8;
    int v[8];
    if (base + 8 <= n) {
        int4 a = *(const int4*)(deg + base);
        int4 b = *(const int4*)(deg + base + 4);
        v[0] = a.x; v[1] = a.y; v[2] = a.z; v[3] = a.w;
        v[4] = b.x; v[5] = b.y; v[6] = b.z; v[7] = b.w;
    } else {
        for (int i = 0; i < 8; ++i) v[i] = (base + i < n) ? deg[base + i] : 0;
    }
    int s = 0;
    #pragma unroll
    for (int i = 0; i < 8; ++i) s += v[i];
    __shared__ int sm[256];
    sm[t] = s;
    __syncthreads();
    #pragma unroll
    for (int off = 1; off < 256; off <<= 1) {
        int y = (t >= off) ? sm[t - off] : 0;
        __syncthreads();
        sm[t] += y;
        __syncthreads();
    }
    int run = bsum[rel * NB + blockIdx.x] + sm[t] - s;
    #pragma unroll
    for (int i = 0; i < 8; ++i) {
        if (base + i < n) rp[base + i] = run;
        run += v[i];
    }
}

// ---------------------------------------------------------------- phase B2: per-block scatter offsets
__global__ void offsets_kernel(const unsigned int* __restrict__ histG,
                               const int* __restrict__ rpS, const int* __restrict__ rpU,
                               int n, int* __restrict__ offsG /* [2][NBLK][n] */) {
    const int rel = blockIdx.y;
    int i = blockIdx.x * 256 + threadIdx.x;
    if (i >= n) return;
    const unsigned int* hg = histG + (size_t)rel * NBLK * n;
    int* og = offsG + (size_t)rel * NBLK * n;
    int run = (rel ? rpU : rpS)[i];
    #pragma unroll
    for (int b = 0; b < NBLK; ++b) {
        og[(size_t)b * n + i] = run;
        run += (int)(hg[(size_t)b * n + i] >> 16);
    }
}

// ---------------------------------------------------------------- phase C: CSR scatter (LDS atomics only)
__global__ __launch_bounds__(256) void csr_scatter_kernel(
    const int* __restrict__ sS, const int* __restrict__ dS,
    const int* __restrict__ sU, const int* __restrict__ dU,
    int Es, int Eu, int n, const int* __restrict__ offsG,
    int* __restrict__ csrS, int* __restrict__ csrU) {
    __shared__ int off[MAXN];
    const int rel = blockIdx.y;
    const int* src = rel ? sU : sS;
    const int* dst = rel ? dU : dS;
    int* csr = rel ? csrU : csrS;
    int E = rel ? Eu : Es;
    int b = blockIdx.x;
    int chunk = (E + NBLK - 1) / NBLK;  // MUST match hist_kernel
    int beg = b * chunk;
    int end = min(E, beg + chunk);
    const int* og = offsG + ((size_t)rel * NBLK + b) * n;
    for (int i = threadIdx.x; i < n; i += 256) off[i] = og[i];
    __syncthreads();
    for (int i = beg + threadIdx.x; i < end; i += 256) {
        int pos = atomicAdd(&off[dst[i]], 1);
        csr[pos] = src[i];
    }
}

// ---------------------------------------------------------------- pull aggregation (both relations)
// One wave per (dst node, relation); lane owns a float4 of the 256-dim row.
__global__ __launch_bounds__(256) void pull_agg2_kernel(
    const float4* __restrict__ xin,
    const int* __restrict__ csrS, const int* __restrict__ csrU,
    const int* __restrict__ rpS, const int* __restrict__ rpU,
    const float* __restrict__ soutS, const float* __restrict__ soutU,
    const float* __restrict__ sinS, const float* __restrict__ sinU,
    float4* __restrict__ out /* [n][128], rel U at +64 */, int n) {
    const int rel = blockIdx.y;
    const int* csr = rel ? csrU : csrS;
    const int* rp = rel ? rpU : rpS;
    const float* sout = rel ? soutU : soutS;
    const float* sin = rel ? sinU : sinS;
    int wid = blockIdx.x * 4 + (threadIdx.x >> 6);
    int lane = threadIdx.x & 63;
    if (wid >= n) return;
    int beg = rp[wid], end = rp[wid + 1];
    float ax = 0.f, ay = 0.f, az = 0.f, aw = 0.f;
    for (int eb = beg; eb < end; eb += 64) {
        int cnt = end - eb;
        if (cnt > 64) cnt = 64;
        int myu = 0;
        float myw = 0.f;
        if (lane < cnt) {
            myu = csr[eb + lane];
            myw = sout[myu];
        }
        for (int j = 0; j < cnt; ++j) {
            int u = __shfl(myu, j);
            float w = __shfl(myw, j);
            float4 a = xin[u * 64 + lane];
            ax += w * a.x;
            ay += w * a.y;
            az += w * a.z;
            aw += w * a.w;
        }
    }
    float si = sin[wid];
    out[(size_t)wid * 128 + rel * 64 + lane] = make_float4(si * ax, si * ay, si * az, si * aw);
}

// ---------------------------------------------------------------- single-relation pull (fallback path)
__global__ __launch_bounds__(256) void pull_agg_kernel(
    const float4* __restrict__ xin, const int* __restrict__ csr,
    const int* __restrict__ rp, const float* __restrict__ sout,
    const float* __restrict__ sin, float4* __restrict__ out, int n) {
    int wid = blockIdx.x * 4 + (threadIdx.x >> 6);
    int lane = threadIdx.x & 63;
    if (wid >= n) return;
    int beg = rp[wid], end = rp[wid + 1];
    float ax = 0.f, ay = 0.f, az = 0.f, aw = 0.f;
    for (int eb = beg; eb < end; eb += 64) {
        int cnt = end - eb;
        if (cnt > 64) cnt = 64;
        int myu = 0;
        float myw = 0.f;
        if (lane < cnt) {
            myu = csr[eb + lane];
            myw = sout[myu];
        }
        for (int j = 0; j < cnt; ++j) {
            int u = __shfl(myu, j);
            float w = __shfl(myw, j);
            float4 a = xin[u * 64 + lane];
            ax += w * a.x;
            ay += w * a.y;
            az += w * a.z;
            aw += w * a.w;
        }
    }
    float si = sin[wid];
    out[(size_t)wid * 64 + lane] = make_float4(si * ax, si * ay, si * az, si * aw);
}

// ---------------------------------------------------------------- fp32 GEMM
// C[M x 256] (+)= A[M x K] @ [B0;B1][K x 256] (+bias) (+relu)
template <int BETA0, int RELU>
__global__ __launch_bounds__(256) void gemm_kernel(
    const float* __restrict__ A, const float* __restrict__ B0,
    const float* __restrict__ B1, const float* __restrict__ bias,
    float* __restrict__ C, int M, int KB, int lda4) {
    __shared__ float At[16][132];
    __shared__ float Bs[16][64];
    int tid = threadIdx.x;
    int ty = tid >> 3;
    int tx = tid & 7;
    int m0 = blockIdx.x * 128;
    int n0 = blockIdx.y * 64;
    const float4* A4 = (const float4*)A;
    const float4* B04 = (const float4*)B0;
    const float4* B14 = (const float4*)B1;
    float acc[4][8] = {};

    for (int ko = 0; ko < KB; ++ko) {
        #pragma unroll
        for (int q = 0; q < 2; ++q) {
            int idx = q * 256 + tid;
            int row = idx & 127;
            int kc = idx >> 7;
            float4 av = make_float4(0.f, 0.f, 0.f, 0.f);
            int gm = m0 + row;
            if (gm < M) av = A4[(size_t)gm * lda4 + ko * 4 + kc];
            At[kc * 4 + 0][row] = av.x;
            At[kc * 4 + 1][row] = av.y;
            At[kc * 4 + 2][row] = av.z;
            At[kc * 4 + 3][row] = av.w;
        }
        {
            int brow = tid >> 4;
            int bc = tid & 15;
            int kg = ko * 16 + brow;
            const float4* Brow = (kg < 256) ? (B04 + (size_t)kg * 64)
                                            : (B14 + (size_t)(kg - 256) * 64);
            *(float4*)&Bs[brow][bc * 4] = Brow[(n0 >> 2) + bc];
        }
        __syncthreads();
        #pragma unroll
        for (int k = 0; k < 16; ++k) {
            float4 a = *(const float4*)&At[k][ty * 4];
            float4 b0 = *(const float4*)&Bs[k][tx * 8];
            float4 b1 = *(const float4*)&Bs[k][tx * 8 + 4];
            float ar[4] = {a.x, a.y, a.z, a.w};
            float br[8] = {b0.x, b0.y, b0.z, b0.w, b1.x, b1.y, b1.z, b1.w};
            #pragma unroll
            for (int i = 0; i < 4; ++i)
                #pragma unroll
                for (int j = 0; j < 8; ++j)
                    acc[i][j] += ar[i] * br[j];
        }
        __syncthreads();
    }

    float bcol[8];
    if (BETA0) {
        #pragma unroll
        for (int j = 0; j < 8; ++j) bcol[j] = bias[n0 + tx * 8 + j];
    }
    #pragma unroll
    for (int i = 0; i < 4; ++i) {
        int gm = m0 + ty * 4 + i;
        if (gm >= M) continue;
        float4* Crow = (float4*)&C[(size_t)gm * 256 + n0 + tx * 8];
        float v[8];
        #pragma unroll
        for (int j = 0; j < 8; ++j) v[j] = acc[i][j] + (BETA0 ? bcol[j] : 0.f);
        if (!BETA0) {
            float4 c0 = Crow[0], c1 = Crow[1];
            v[0] += c0.x; v[1] += c0.y; v[2] += c0.z; v[3] += c0.w;
            v[4] += c1.x; v[5] += c1.y; v[6] += c1.z; v[7] += c1.w;
        }
        if (RELU) {
            #pragma unroll
            for (int j = 0; j < 8; ++j) v[j] = fmaxf(v[j], 0.f);
        }
        Crow[0] = make_float4(v[0], v[1], v[2], v[3]);
        Crow[1] = make_float4(v[4], v[5], v[6], v[7]);
    }
}

// ---------------------------------------------------------------- launch
extern "C" void kernel_launch(void* const* d_in, const int* in_sizes, int n_in,
                              void* d_out, int out_size, void* d_ws, size_t ws_size,
                              hipStream_t stream) {
    const float* x   = (const float*)d_in[0];
    const int* sS    = (const int*)d_in[1];
    const int* dS    = (const int*)d_in[2];
    const int* sU    = (const int*)d_in[3];
    const int* dU    = (const int*)d_in[4];
    const float* W1s = (const float*)d_in[5];
    const float* b1s = (const float*)d_in[6];
    const float* W1u = (const float*)d_in[7];
    const float* b1u = (const float*)d_in[8];
    const float* W2s = (const float*)d_in[9];
    const float* b2s = (const float*)d_in[10];
    const float* W2u = (const float*)d_in[11];
    const float* b2u = (const float*)d_in[12];
    float* out = (float*)d_out;

    const int n  = in_sizes[0] / 256;
    const int Es = in_sizes[1];
    const int Eu = in_sizes[3];
    const int NB = (n + SCHUNK - 1) / SCHUNK;

    char* ws = (char*)d_ws;
    size_t off = 0;
    auto alloc = [&](size_t bytes) -> void* {
        off = (off + 255) & ~(size_t)255;
        void* p = ws + off;
        off += bytes;
        return p;
    };

    unsigned int* histG = (unsigned int*)alloc((size_t)2 * NBLK * n * 4);
    int* offsG   = (int*)alloc((size_t)2 * NBLK * n * 4);
    int* rpS     = (int*)alloc((size_t)(n + 1) * 4);
    int* rpU     = (int*)alloc((size_t)(n + 1) * 4);
    float* sOutS = (float*)alloc((size_t)n * 4);
    float* sInS  = (float*)alloc((size_t)n * 4);
    float* sOutU = (float*)alloc((size_t)n * 4);
    float* sInU  = (float*)alloc((size_t)n * 4);
    int* degInS  = (int*)alloc((size_t)n * 4);
    int* degInU  = (int*)alloc((size_t)n * 4);
    float* bsum1 = (float*)alloc(256 * 4);
    float* bsum2 = (float*)alloc(256 * 4);
    int* bsumBlk = (int*)alloc((size_t)2 * NB * 4);
    int* csrS    = (int*)alloc((size_t)Es * 4);
    int* csrU    = (int*)alloc((size_t)Eu * 4);

    size_t fixed = off;
    size_t need_fused = ((fixed + 255) & ~(size_t)255) + (size_t)n * 512 * 4 + 256 +
                        (size_t)n * 256 * 4 + 256;
    bool fused = need_fused <= ws_size;
    float* aggCat = (float*)alloc((size_t)n * (fused ? 512 : 256) * 4);
    float* h      = (float*)alloc((size_t)n * 256 * 4);

    // preprocessing: histogram counting sort (no global atomics anywhere)
    bias_sum_kernel<<<1, 256, 0, stream>>>(b1s, b1u, b2s, b2u, bsum1, bsum2);
    dim3 hg(NBLK, 2);
    hist_kernel<<<hg, 256, 0, stream>>>(sS, dS, sU, dU, Es, Eu, n, histG);
    dim3 tg((n + 255) / 256, 2);
    totals_kernel<<<tg, 256, 0, stream>>>(histG, n, sOutS, sInS, sOutU, sInU, degInS, degInU);
    dim3 sg(NB, 2);
    scan_part_kernel<<<sg, 256, 0, stream>>>(degInS, degInU, n, NB, bsumBlk);
    scan_mid_kernel<<<1, 64, 0, stream>>>(bsumBlk, NB, rpS, rpU, n);
    scan_final_kernel<<<sg, 256, 0, stream>>>(degInS, degInU, bsumBlk, n, NB, rpS, rpU);
    offsets_kernel<<<tg, 256, 0, stream>>>(histG, rpS, rpU, n, offsG);
    csr_scatter_kernel<<<hg, 256, 0, stream>>>(sS, dS, sU, dU, Es, Eu, n, offsG, csrS, csrU);

    const float4* x4 = (const float4*)x;
    const float4* h4 = (const float4*)h;
    float4* agg4 = (float4*)aggCat;
    int aggGrid = (n + 3) / 4;
    dim3 pg(aggGrid, 2);
    dim3 ggrid((n + 127) / 128, 4);

    if (fused) {
        pull_agg2_kernel<<<pg, 256, 0, stream>>>(x4, csrS, csrU, rpS, rpU,
                                                 sOutS, sOutU, sInS, sInU, agg4, n);
        gemm_kernel<1, 1><<<ggrid, 256, 0, stream>>>(aggCat, W1s, W1u, bsum1, h, n, 32, 128);
        pull_agg2_kernel<<<pg, 256, 0, stream>>>(h4, csrS, csrU, rpS, rpU,
                                                 sOutS, sOutU, sInS, sInU, agg4, n);
        gemm_kernel<1, 0><<<ggrid, 256, 0, stream>>>(aggCat, W2s, W2u, bsum2, out, n, 32, 128);
    } else {
        pull_agg_kernel<<<aggGrid, 256, 0, stream>>>(x4, csrS, rpS, sOutS, sInS, agg4, n);
        gemm_kernel<1, 0><<<ggrid, 256, 0, stream>>>(aggCat, W1s, W1s, bsum1, h, n, 16, 64);
        pull_agg_kernel<<<aggGrid, 256, 0, stream>>>(x4, csrU, rpU, sOutU, sInU, agg4, n);
        gemm_kernel<0, 1><<<ggrid, 256, 0, stream>>>(aggCat, W1u, W1u, nullptr, h, n, 16, 64);
        pull_agg_kernel<<<aggGrid, 256, 0, stream>>>(h4, csrS, rpS, sOutS, sInS, agg4, n);
        gemm_kernel<1, 0><<<ggrid, 256, 0, stream>>>(aggCat, W2s, W2s, bsum2, out, n, 16, 64);
        pull_agg_kernel<<<aggGrid, 256, 0, stream>>>(h4, csrU, rpU, sOutU, sInU, agg4, n);
        gemm_kernel<0, 0><<<ggrid, 256, 0, stream>>>(aggCat, W2u, W2u, nullptr, out, n, 16, 64);
    }
}